// Round 11
// baseline (3118071.289 us; speedup 1.0000x reference)
//
#include <hip/hip_runtime.h>

// SimpleLSTM B=256, T=512, I=3, H=512. out = fc(h_T).
// R11 = R10 with the h-exchange + barrier moved from LLC (sc0 sc1 / agent
// atomics) to per-XCD L2 (sc0-only / L2 atomics). Batch group = physical XCD:
// each wg reads HW_REG_XCC_ID and claims slot hb in [0,32) via one-time atomic.
// Capacity (155KB LDS -> 1 wg/CU, 256 wgs co-resident) guarantees exactly 32
// wgs per XCD, so grouping is correct for ANY dispatch->XCD mapping.
// All h stores/loads sc0-only (L2-coherent within XCD, ~3x lower latency,
// ~2.4x higher BW than LLC). Barrier counter = L2 atomic. Bounded poll.
// Everything else identical to R10 (fragment-linear W, pad-20 gates2,
// split-bf16 MFMA, batched loads + single vmcnt drain).

#define Hh   512
#define Bsz  256
#define Tt   512

#define MB   32
#define HS   16
#define NROW 64
#define NTHR 512
#define NWG  256

typedef float f32x4 __attribute__((ext_vector_type(4)));
typedef short s16x8 __attribute__((ext_vector_type(8)));
typedef unsigned long long u64;

#define PLANE_SZ (2 * Bsz * Hh * 2)          // 512 KB
#define HHI_OFF  0
#define HLO_OFF  (HHI_OFF + PLANE_SZ)
#define BAR_OFF  (HLO_OFF + PLANE_SZ)
#define CTRL_UINTS 512                       // [bb*16]: barrier, [256+xcd*16]: claim

__device__ __forceinline__ float sigm(float v)  { return 1.0f / (1.0f + __expf(-v)); }
__device__ __forceinline__ float tanhx(float v) { return 2.0f / (1.0f + __expf(-2.0f * v)) - 1.0f; }

__device__ __forceinline__ ushort f2bf(float f) {   // RNE
  unsigned u = __float_as_uint(f);
  return (ushort)((u + 0x7FFFu + ((u >> 16) & 1u)) >> 16);
}
__device__ __forceinline__ float bf2f(ushort u) {
  return __uint_as_float((unsigned)u << 16);
}

// L2-coherent (XCD-local) 16B load: sc0 only (bypass L1, hit L2).
#define GLOAD(dst, base, imm)                                            \
  asm volatile("global_load_dwordx4 %0, %1, off offset:%c2 sc0"          \
               : "=v"(dst) : "v"(base), "i"(imm))

// L2-coherent 4B store.
#define GSTORE_W(addr, val)                                              \
  asm volatile("global_store_dword %0, %1, off sc0" :: "v"(addr), "v"(val))

// XCD-local barrier: drain stores to L2, converge, L2 atomic increment,
// leader polls with sc0 loads, __syncthreads broadcasts release.
// Bounded spin: on coherence failure -> break (wrong answer, not a hang).
__device__ __forceinline__ void group_barrier(unsigned* bar, int tid, unsigned target) {
  asm volatile("s_waitcnt vmcnt(0)" ::: "memory");
  __syncthreads();
  if (tid == 0) {
    unsigned one = 1u;
    asm volatile("global_atomic_add %0, %1, off" :: "v"(bar), "v"(one) : "memory");
    unsigned v = 0;
    int spins = 0;
    do {
      __builtin_amdgcn_s_sleep(2);
      asm volatile("global_load_dword %0, %1, off sc0\n\t"
                   "s_waitcnt vmcnt(0)" : "=v"(v) : "v"(bar) : "memory");
    } while (v < target && ++spins < (1 << 16));
  }
  __syncthreads();
}

__global__ void init_ws(unsigned* ctrl) {
  ctrl[threadIdx.x] = 0u;
}

__global__ __launch_bounds__(NTHR, 1)
void lstm_kernel(const float* __restrict__ x,   const float* __restrict__ Wih,
                 const float* __restrict__ Whh, const float* __restrict__ bih,
                 const float* __restrict__ bhh, const float* __restrict__ fcw,
                 const float* __restrict__ fcb, float* __restrict__ out,
                 char* __restrict__ ws)
{
  const int tid = threadIdx.x;

  ushort*   hhi  = (ushort*)(ws + HHI_OFF);
  ushort*   hlo  = (ushort*)(ws + HLO_OFF);
  unsigned* ctrl = (unsigned*)(ws + BAR_OFF);

  // ---- XCD self-identification + slot claim (one-time, agent scope) ----
  __shared__ int xcc_s, hb_s;
  if (tid == 0) {
    int xcc;
    asm volatile("s_getreg_b32 %0, hwreg(HW_REG_XCC_ID)" : "=s"(xcc));
    xcc &= 7;
    xcc_s = xcc;
    hb_s = (int)__hip_atomic_fetch_add(ctrl + 256 + xcc * 16, 1u,
                                       __ATOMIC_RELAXED, __HIP_MEMORY_SCOPE_AGENT);
  }
  __syncthreads();
  const int bb = xcc_s;        // batch group = physical XCD
  const int hb = hb_s & 31;    // hidden slot within XCD (0..31 by capacity)
  const int j0 = hb * HS;
  const int b0 = bb * MB;
  unsigned* bar = ctrl + bb * 16;

  // Fragment-linear W: whiF[((q*16 + kblk)*64 + lane)*8 + e] =
  //   W[q*16 + (lane&15)][kblk*32 + (lane>>4)*8 + e],  kblk = 0..15
  __shared__ ushort whiF[4 * 16 * 64 * 8];   // 64 KB
  __shared__ ushort wloF[4 * 16 * 64 * 8];   // 64 KB
  __shared__ float  gates2[2][4][MB][20];    // two-stage K-partials, pad 20
  __shared__ float  wih_s[NROW][3];
  __shared__ float  bsum[NROW];
  __shared__ float  xs[MB][3];
  __shared__ ushort hstg[MB][16];
  __shared__ ushort lstg[MB][16];

  if (tid < NROW) {
    int qq = tid >> 4, jj = tid & 15;
    int grow = qq * Hh + j0 + jj;
    wih_s[tid][0] = Wih[grow * 3 + 0];
    wih_s[tid][1] = Wih[grow * 3 + 1];
    wih_s[tid][2] = Wih[grow * 3 + 2];
    bsum[tid] = bih[grow] + bhh[grow];
  }

  for (int idx = tid; idx < NROW * 64; idx += NTHR) {
    int row = idx >> 6, seg = idx & 63;
    int qq = row >> 4, jj = row & 15;
    const float* src = Whh + (size_t)(qq * Hh + j0 + jj) * Hh + seg * 8;
    float4 w0 = *(const float4*)(src);
    float4 w1 = *(const float4*)(src + 4);
    float wv[8] = {w0.x, w0.y, w0.z, w0.w, w1.x, w1.y, w1.z, w1.w};
    unsigned uhi[4], ulo[4];
    #pragma unroll
    for (int p = 0; p < 4; ++p) {
      ushort h0 = f2bf(wv[2*p]),   h1 = f2bf(wv[2*p+1]);
      ushort l0 = f2bf(wv[2*p]   - bf2f(h0));
      ushort l1 = f2bf(wv[2*p+1] - bf2f(h1));
      uhi[p] = (unsigned)h0 | ((unsigned)h1 << 16);
      ulo[p] = (unsigned)l0 | ((unsigned)l1 << 16);
    }
    int kblk = seg >> 2, lkk = seg & 3;
    int dst = ((qq * 16 + kblk) * 64 + lkk * 16 + jj) * 8;
    *(uint4*)&whiF[dst] = make_uint4(uhi[0], uhi[1], uhi[2], uhi[3]);
    *(uint4*)&wloF[dst] = make_uint4(ulo[0], ulo[1], ulo[2], ulo[3]);
  }

  // ---- zero h_0 slice (buffer 0), L2-local stores ----
  if (tid < 256) {
    int b = tid >> 3, jp = tid & 7;
    size_t wordo = ((size_t)(b0 + b) * Hh + j0) / 2 + jp;
    unsigned z = 0;
    GSTORE_W((unsigned*)hhi + wordo, z);
    GSTORE_W((unsigned*)hlo + wordo, z);
  }
  group_barrier(bar, tid, 32u);

  const int l   = tid & 63;
  const int wid = tid >> 6;
  const int m   = wid >> 2;            // batch half (0..1)
  const int ks  = wid & 3;             // K quarter (0..3)
  const int lm  = l & 15;
  const int lk  = l >> 4;              // 0..3

  const size_t aoff  = (size_t)(b0 + m * 16 + lm) * Hh + ks * 128 + lk * 8;
  const int    wq0   = ks * 2048 + l * 8;   // + q*8192 + u*512 (ushort idx)

  const int cb = tid >> 4;
  const int cj = tid & 15;
  float c_state = 0.0f;

  int cur = 0;
  for (int t = 0; t < Tt; ++t) {
    if (tid < MB * 3) {
      int b = tid / 3, ii = tid - b * 3;
      xs[b][ii] = x[(size_t)(b0 + b) * (Tt * 3) + t * 3 + ii];
    }

    // ---- 8 pipelined A loads (distinct K-quarter, hi+lo, L2-local) ----
    const char* pH = (const char*)(hhi + (size_t)cur * Bsz * Hh + aoff);
    const char* pL = (const char*)(hlo + (size_t)cur * Bsz * Hh + aoff);
    f32x4 AH[4], AL[4];
    GLOAD(AH[0], pH, 0);  GLOAD(AH[1], pH, 64);  GLOAD(AH[2], pH, 128); GLOAD(AH[3], pH, 192);
    GLOAD(AL[0], pL, 0);  GLOAD(AL[1], pL, 64);  GLOAD(AL[2], pL, 128); GLOAD(AL[3], pL, 192);
    asm volatile("s_waitcnt vmcnt(0)" ::: "memory");
    __builtin_amdgcn_sched_barrier(0);

    // ---- 4 quadrants x 4 k-blocks x 3 split terms = 48 MFMAs ----
    f32x4 acc0 = {0.f,0.f,0.f,0.f}, acc1 = {0.f,0.f,0.f,0.f};
    f32x4 acc2 = {0.f,0.f,0.f,0.f}, acc3 = {0.f,0.f,0.f,0.f};
    #pragma unroll
    for (int u = 0; u < 4; ++u) {
      s16x8 ah = __builtin_bit_cast(s16x8, AH[u]);
      s16x8 al = __builtin_bit_cast(s16x8, AL[u]);
      const int fo = wq0 + u * 512;
      {
        s16x8 bh = *(const s16x8*)&whiF[0 * 8192 + fo];
        s16x8 bl = *(const s16x8*)&wloF[0 * 8192 + fo];
        acc0 = __builtin_amdgcn_mfma_f32_16x16x32_bf16(ah, bh, acc0, 0, 0, 0);
        acc0 = __builtin_amdgcn_mfma_f32_16x16x32_bf16(ah, bl, acc0, 0, 0, 0);
        acc0 = __builtin_amdgcn_mfma_f32_16x16x32_bf16(al, bh, acc0, 0, 0, 0);
      }
      {
        s16x8 bh = *(const s16x8*)&whiF[1 * 8192 + fo];
        s16x8 bl = *(const s16x8*)&wloF[1 * 8192 + fo];
        acc1 = __builtin_amdgcn_mfma_f32_16x16x32_bf16(ah, bh, acc1, 0, 0, 0);
        acc1 = __builtin_amdgcn_mfma_f32_16x16x32_bf16(ah, bl, acc1, 0, 0, 0);
        acc1 = __builtin_amdgcn_mfma_f32_16x16x32_bf16(al, bh, acc1, 0, 0, 0);
      }
      {
        s16x8 bh = *(const s16x8*)&whiF[2 * 8192 + fo];
        s16x8 bl = *(const s16x8*)&wloF[2 * 8192 + fo];
        acc2 = __builtin_amdgcn_mfma_f32_16x16x32_bf16(ah, bh, acc2, 0, 0, 0);
        acc2 = __builtin_amdgcn_mfma_f32_16x16x32_bf16(ah, bl, acc2, 0, 0, 0);
        acc2 = __builtin_amdgcn_mfma_f32_16x16x32_bf16(al, bh, acc2, 0, 0, 0);
      }
      {
        s16x8 bh = *(const s16x8*)&whiF[3 * 8192 + fo];
        s16x8 bl = *(const s16x8*)&wloF[3 * 8192 + fo];
        acc3 = __builtin_amdgcn_mfma_f32_16x16x32_bf16(ah, bh, acc3, 0, 0, 0);
        acc3 = __builtin_amdgcn_mfma_f32_16x16x32_bf16(ah, bl, acc3, 0, 0, 0);
        acc3 = __builtin_amdgcn_mfma_f32_16x16x32_bf16(al, bh, acc3, 0, 0, 0);
      }
    }

    // ---- two-stage K-partial reduction in LDS ----
    const int rrow = m * 16 + lk * 4;
    if (ks < 2) {
      #pragma unroll
      for (int r = 0; r < 4; ++r) {
        gates2[ks][0][rrow + r][lm] = acc0[r];
        gates2[ks][1][rrow + r][lm] = acc1[r];
        gates2[ks][2][rrow + r][lm] = acc2[r];
        gates2[ks][3][rrow + r][lm] = acc3[r];
      }
    }
    __syncthreads();
    if (ks >= 2) {
      #pragma unroll
      for (int r = 0; r < 4; ++r) {
        gates2[ks - 2][0][rrow + r][lm] += acc0[r];
        gates2[ks - 2][1][rrow + r][lm] += acc1[r];
        gates2[ks - 2][2][rrow + r][lm] += acc2[r];
        gates2[ks - 2][3][rrow + r][lm] += acc3[r];
      }
    }
    __syncthreads();

    // ---- gate combine ----
    {
      float xv0 = xs[cb][0], xv1 = xs[cb][1], xv2 = xs[cb][2];
      float pre[4];
      #pragma unroll
      for (int qq = 0; qq < 4; ++qq) {
        int r = qq * 16 + cj;
        pre[qq] = gates2[0][qq][cb][cj] + gates2[1][qq][cb][cj] + bsum[r]
                + xv0 * wih_s[r][0] + xv1 * wih_s[r][1] + xv2 * wih_s[r][2];
      }
      float ig = sigm(pre[0]), fg = sigm(pre[1]);
      float gg = tanhx(pre[2]), og = sigm(pre[3]);
      c_state = fg * c_state + ig * gg;
      float hv = og * tanhx(c_state);
      ushort uh = f2bf(hv);
      hstg[cb][cj] = uh;
      lstg[cb][cj] = f2bf(hv - bf2f(uh));
    }
    __syncthreads();

    // ---- packed L2-local store of h slice ----
    if (tid < 256) {
      int b = tid >> 3, jp = tid & 7;
      unsigned wh = (unsigned)hstg[b][2 * jp] | ((unsigned)hstg[b][2 * jp + 1] << 16);
      unsigned wl = (unsigned)lstg[b][2 * jp] | ((unsigned)lstg[b][2 * jp + 1] << 16);
      size_t wordo = ((size_t)(cur ^ 1) * Bsz * Hh + (size_t)(b0 + b) * Hh + j0) / 2 + jp;
      GSTORE_W((unsigned*)hhi + wordo, wh);
      GSTORE_W((unsigned*)hlo + wordo, wl);
    }

    group_barrier(bar, tid, 32u * (t + 2));
    cur ^= 1;
  }

  // ---- epilogue: hb==0 wg of each XCD computes FC (L2-local loads) ----
  if (hb == 0) {
    const u64* Hf = (const u64*)(hhi + (size_t)cur * Bsz * Hh);
    const u64* Lf = (const u64*)(hlo + (size_t)cur * Bsz * Hh);
    int b = tid >> 4, lj = tid & 15;
    float p = 0.0f;
    for (int jq = lj; jq < Hh / 4; jq += 16) {
      const u64* pa = Hf + (size_t)(b0 + b) * (Hh / 4) + jq;
      const u64* pb = Lf + (size_t)(b0 + b) * (Hh / 4) + jq;
      u64 uh, ul;
      asm volatile("global_load_dwordx2 %0, %1, off sc0" : "=v"(uh) : "v"(pa));
      asm volatile("global_load_dwordx2 %0, %1, off sc0" : "=v"(ul) : "v"(pb));
      asm volatile("s_waitcnt vmcnt(0)" ::: "memory");
      #pragma unroll
      for (int e = 0; e < 4; ++e) {
        float hv = bf2f((ushort)(uh >> (16 * e))) + bf2f((ushort)(ul >> (16 * e)));
        p += hv * fcw[4 * jq + e];
      }
    }
    __syncthreads();
    ((float*)gates2)[tid] = p;
    __syncthreads();
    if (lj == 0) {
      float s = 0.0f;
      #pragma unroll
      for (int r = 0; r < 16; ++r) s += ((float*)gates2)[(b << 4) + r];
      out[b0 + b] = s + fcb[0];
    }
  }
}

extern "C" void kernel_launch(void* const* d_in, const int* in_sizes, int n_in,
                              void* d_out, int out_size, void* d_ws, size_t ws_size,
                              hipStream_t stream) {
  const float* x   = (const float*)d_in[0];
  const float* Wih = (const float*)d_in[1];
  const float* Whh = (const float*)d_in[2];
  const float* bih = (const float*)d_in[3];
  const float* bhh = (const float*)d_in[4];
  const float* fcw = (const float*)d_in[5];
  const float* fcb = (const float*)d_in[6];
  float* out = (float*)d_out;
  char*  ws  = (char*)d_ws;

  hipLaunchKernelGGL(init_ws, dim3(1), dim3(CTRL_UINTS), 0, stream,
                     (unsigned*)(ws + BAR_OFF));
  hipLaunchKernelGGL(lstm_kernel, dim3(NWG), dim3(NTHR), 0, stream,
                     x, Wih, Whh, bih, bhh, fcw, fcb, out, ws);
}

// Round 12
// 2402.793 us; speedup vs baseline: 1297.6861x; 1297.6861x over previous
//
#include <hip/hip_runtime.h>

// SimpleLSTM B=256, T=512, I=3, H=512. out = fc(h_T).
// R12 = R10 (known-pass 2.458ms; LLC sc0sc1 exchange) + two fixes:
//  1. Flag-array barrier: arrival = parallel store to own flag word
//     (no RMW serialization on one LLC line); wave0 polls all 32 flags
//     (1 vector load/iter + __all). Monotone flags -> stale reads safe.
//  2. Combine threads store h directly (2B/lane, coalesced) -> drops
//     hstg/lstg staging and one __syncthreads per step.
// R11 lesson kept: sync MUST go through LLC (sc0 sc1); XCD L2 is not a
// usable sync domain (atomic and sc0 poll never meet -> 3.1s timeout run).
// Everything else identical to R10: fragment-linear W LDS, pad-20 gates2,
// waves (m, ks), split-bf16 MFMA, batched GLOAD sc0sc1 + single vmcnt drain.

#define Hh   512
#define Bsz  256
#define Tt   512

#define MB   32
#define HS   16
#define NROW 64
#define NTHR 512
#define NWG  256

typedef float f32x4 __attribute__((ext_vector_type(4)));
typedef short s16x8 __attribute__((ext_vector_type(8)));
typedef unsigned long long u64;

#define PLANE_SZ (2 * Bsz * Hh * 2)          // 512 KB
#define HHI_OFF  0
#define HLO_OFF  (HHI_OFF + PLANE_SZ)
#define BAR_OFF  (HLO_OFF + PLANE_SZ)
#define CTRL_UINTS 512                       // [256 + bb*32 + hb] = arrival flags

__device__ __forceinline__ float sigm(float v)  { return 1.0f / (1.0f + __expf(-v)); }
__device__ __forceinline__ float tanhx(float v) { return 2.0f / (1.0f + __expf(-2.0f * v)) - 1.0f; }

__device__ __forceinline__ ushort f2bf(float f) {   // RNE
  unsigned u = __float_as_uint(f);
  return (ushort)((u + 0x7FFFu + ((u >> 16) & 1u)) >> 16);
}
__device__ __forceinline__ float bf2f(ushort u) {
  return __uint_as_float((unsigned)u << 16);
}

#define GLOAD(dst, base, imm)                                            \
  asm volatile("global_load_dwordx4 %0, %1, off offset:%c2 sc0 sc1"      \
               : "=v"(dst) : "v"(base), "i"(imm))

// Flag barrier at LLC. Arrival: after all waves drain their h-stores
// (vmcnt(0) + syncthreads), tid 0 stores (t-monotone) target to its own
// flag word. Exit: wave 0, lane i polls flag[i&31]; __all releases; second
// syncthreads broadcasts. Stale reads only delay (monotone), never corrupt.
__device__ __forceinline__ void group_barrier(unsigned* flags, int hb, int tid, unsigned target) {
  asm volatile("s_waitcnt vmcnt(0)" ::: "memory");
  __syncthreads();
  if (tid == 0) {
    unsigned v = target;
    asm volatile("global_store_dword %0, %1, off sc0 sc1"
                 :: "v"(flags + hb), "v"(v) : "memory");
  }
  if (tid < 64) {
    const unsigned* fp = flags + (tid & 31);
    unsigned v;
    do {
      __builtin_amdgcn_s_sleep(1);
      asm volatile("global_load_dword %0, %1, off sc0 sc1\n\t"
                   "s_waitcnt vmcnt(0)" : "=v"(v) : "v"(fp) : "memory");
    } while (!__all((int)(v >= target)));
  }
  __syncthreads();
}

__global__ void init_ws(unsigned* ctrl) {
  ctrl[threadIdx.x] = 0u;
}

__global__ __launch_bounds__(NTHR, 2)
void lstm_kernel(const float* __restrict__ x,   const float* __restrict__ Wih,
                 const float* __restrict__ Whh, const float* __restrict__ bih,
                 const float* __restrict__ bhh, const float* __restrict__ fcw,
                 const float* __restrict__ fcb, float* __restrict__ out,
                 char* __restrict__ ws)
{
  const int tid = threadIdx.x;
  const int wg  = blockIdx.x;
  const int bb  = wg & 7;
  const int hb  = wg >> 3;
  const int j0  = hb * HS;
  const int b0  = bb * MB;

  ushort*   hhi   = (ushort*)(ws + HHI_OFF);
  ushort*   hlo   = (ushort*)(ws + HLO_OFF);
  unsigned* flags = (unsigned*)(ws + BAR_OFF) + 256 + bb * 32;

  // Fragment-linear W: whiF[((q*16 + kblk)*64 + lane)*8 + e] =
  //   W[q*16 + (lane&15)][kblk*32 + (lane>>4)*8 + e],  kblk = 0..15
  __shared__ ushort whiF[4 * 16 * 64 * 8];   // 64 KB
  __shared__ ushort wloF[4 * 16 * 64 * 8];   // 64 KB
  __shared__ float  gates2[2][4][MB][20];    // two-stage K-partials, pad 20
  __shared__ float  wih_s[NROW][3];
  __shared__ float  bsum[NROW];
  __shared__ float  xs[MB][3];

  if (tid < NROW) {
    int qq = tid >> 4, jj = tid & 15;
    int grow = qq * Hh + j0 + jj;
    wih_s[tid][0] = Wih[grow * 3 + 0];
    wih_s[tid][1] = Wih[grow * 3 + 1];
    wih_s[tid][2] = Wih[grow * 3 + 2];
    bsum[tid] = bih[grow] + bhh[grow];
  }

  for (int idx = tid; idx < NROW * 64; idx += NTHR) {
    int row = idx >> 6, seg = idx & 63;
    int qq = row >> 4, jj = row & 15;
    const float* src = Whh + (size_t)(qq * Hh + j0 + jj) * Hh + seg * 8;
    float4 w0 = *(const float4*)(src);
    float4 w1 = *(const float4*)(src + 4);
    float wv[8] = {w0.x, w0.y, w0.z, w0.w, w1.x, w1.y, w1.z, w1.w};
    unsigned uhi[4], ulo[4];
    #pragma unroll
    for (int p = 0; p < 4; ++p) {
      ushort h0 = f2bf(wv[2*p]),   h1 = f2bf(wv[2*p+1]);
      ushort l0 = f2bf(wv[2*p]   - bf2f(h0));
      ushort l1 = f2bf(wv[2*p+1] - bf2f(h1));
      uhi[p] = (unsigned)h0 | ((unsigned)h1 << 16);
      ulo[p] = (unsigned)l0 | ((unsigned)l1 << 16);
    }
    int kblk = seg >> 2, lkk = seg & 3;
    int dst = ((qq * 16 + kblk) * 64 + lkk * 16 + jj) * 8;
    *(uint4*)&whiF[dst] = make_uint4(uhi[0], uhi[1], uhi[2], uhi[3]);
    *(uint4*)&wloF[dst] = make_uint4(ulo[0], ulo[1], ulo[2], ulo[3]);
  }

  // ---- zero h_0 slice (buffer 0) via LLC stores ----
  {
    int b = tid >> 4, jj = tid & 15;
    size_t o = (size_t)(b0 + b) * Hh + j0 + jj;
    __hip_atomic_store(&hhi[o], (ushort)0, __ATOMIC_RELAXED, __HIP_MEMORY_SCOPE_AGENT);
    __hip_atomic_store(&hlo[o], (ushort)0, __ATOMIC_RELAXED, __HIP_MEMORY_SCOPE_AGENT);
  }
  group_barrier(flags, hb, tid, 1u);

  const int l   = tid & 63;
  const int wid = tid >> 6;
  const int m   = wid >> 2;            // batch half (0..1)
  const int ks  = wid & 3;             // K quarter (0..3)
  const int lm  = l & 15;
  const int lk  = l >> 4;              // 0..3

  const size_t aoff  = (size_t)(b0 + m * 16 + lm) * Hh + ks * 128 + lk * 8;
  const int    wq0   = ks * 2048 + l * 8;   // + q*8192 + u*512 (ushort idx)

  const int cb = tid >> 4;
  const int cj = tid & 15;
  float c_state = 0.0f;

  int cur = 0;
  for (int t = 0; t < Tt; ++t) {
    if (tid < MB * 3) {
      int b = tid / 3, ii = tid - b * 3;
      xs[b][ii] = x[(size_t)(b0 + b) * (Tt * 3) + t * 3 + ii];
    }

    // ---- 8 pipelined A loads (distinct K-quarter, hi+lo) ----
    const char* pH = (const char*)(hhi + (size_t)cur * Bsz * Hh + aoff);
    const char* pL = (const char*)(hlo + (size_t)cur * Bsz * Hh + aoff);
    f32x4 AH[4], AL[4];
    GLOAD(AH[0], pH, 0);  GLOAD(AH[1], pH, 64);  GLOAD(AH[2], pH, 128); GLOAD(AH[3], pH, 192);
    GLOAD(AL[0], pL, 0);  GLOAD(AL[1], pL, 64);  GLOAD(AL[2], pL, 128); GLOAD(AL[3], pL, 192);
    asm volatile("s_waitcnt vmcnt(0)" ::: "memory");
    __builtin_amdgcn_sched_barrier(0);

    // ---- 4 quadrants x 4 k-blocks x 3 split terms = 48 MFMAs ----
    f32x4 acc0 = {0.f,0.f,0.f,0.f}, acc1 = {0.f,0.f,0.f,0.f};
    f32x4 acc2 = {0.f,0.f,0.f,0.f}, acc3 = {0.f,0.f,0.f,0.f};
    #pragma unroll
    for (int u = 0; u < 4; ++u) {
      s16x8 ah = __builtin_bit_cast(s16x8, AH[u]);
      s16x8 al = __builtin_bit_cast(s16x8, AL[u]);
      const int fo = wq0 + u * 512;
      {
        s16x8 bh = *(const s16x8*)&whiF[0 * 8192 + fo];
        s16x8 bl = *(const s16x8*)&wloF[0 * 8192 + fo];
        acc0 = __builtin_amdgcn_mfma_f32_16x16x32_bf16(ah, bh, acc0, 0, 0, 0);
        acc0 = __builtin_amdgcn_mfma_f32_16x16x32_bf16(ah, bl, acc0, 0, 0, 0);
        acc0 = __builtin_amdgcn_mfma_f32_16x16x32_bf16(al, bh, acc0, 0, 0, 0);
      }
      {
        s16x8 bh = *(const s16x8*)&whiF[1 * 8192 + fo];
        s16x8 bl = *(const s16x8*)&wloF[1 * 8192 + fo];
        acc1 = __builtin_amdgcn_mfma_f32_16x16x32_bf16(ah, bh, acc1, 0, 0, 0);
        acc1 = __builtin_amdgcn_mfma_f32_16x16x32_bf16(ah, bl, acc1, 0, 0, 0);
        acc1 = __builtin_amdgcn_mfma_f32_16x16x32_bf16(al, bh, acc1, 0, 0, 0);
      }
      {
        s16x8 bh = *(const s16x8*)&whiF[2 * 8192 + fo];
        s16x8 bl = *(const s16x8*)&wloF[2 * 8192 + fo];
        acc2 = __builtin_amdgcn_mfma_f32_16x16x32_bf16(ah, bh, acc2, 0, 0, 0);
        acc2 = __builtin_amdgcn_mfma_f32_16x16x32_bf16(ah, bl, acc2, 0, 0, 0);
        acc2 = __builtin_amdgcn_mfma_f32_16x16x32_bf16(al, bh, acc2, 0, 0, 0);
      }
      {
        s16x8 bh = *(const s16x8*)&whiF[3 * 8192 + fo];
        s16x8 bl = *(const s16x8*)&wloF[3 * 8192 + fo];
        acc3 = __builtin_amdgcn_mfma_f32_16x16x32_bf16(ah, bh, acc3, 0, 0, 0);
        acc3 = __builtin_amdgcn_mfma_f32_16x16x32_bf16(ah, bl, acc3, 0, 0, 0);
        acc3 = __builtin_amdgcn_mfma_f32_16x16x32_bf16(al, bh, acc3, 0, 0, 0);
      }
    }

    // ---- two-stage K-partial reduction in LDS ----
    const int rrow = m * 16 + lk * 4;
    if (ks < 2) {
      #pragma unroll
      for (int r = 0; r < 4; ++r) {
        gates2[ks][0][rrow + r][lm] = acc0[r];
        gates2[ks][1][rrow + r][lm] = acc1[r];
        gates2[ks][2][rrow + r][lm] = acc2[r];
        gates2[ks][3][rrow + r][lm] = acc3[r];
      }
    }
    __syncthreads();
    if (ks >= 2) {
      #pragma unroll
      for (int r = 0; r < 4; ++r) {
        gates2[ks - 2][0][rrow + r][lm] += acc0[r];
        gates2[ks - 2][1][rrow + r][lm] += acc1[r];
        gates2[ks - 2][2][rrow + r][lm] += acc2[r];
        gates2[ks - 2][3][rrow + r][lm] += acc3[r];
      }
    }
    __syncthreads();

    // ---- gate combine + DIRECT coalesced h store (2B/lane) ----
    {
      float xv0 = xs[cb][0], xv1 = xs[cb][1], xv2 = xs[cb][2];
      float pre[4];
      #pragma unroll
      for (int qq = 0; qq < 4; ++qq) {
        int r = qq * 16 + cj;
        pre[qq] = gates2[0][qq][cb][cj] + gates2[1][qq][cb][cj] + bsum[r]
                + xv0 * wih_s[r][0] + xv1 * wih_s[r][1] + xv2 * wih_s[r][2];
      }
      float ig = sigm(pre[0]), fg = sigm(pre[1]);
      float gg = tanhx(pre[2]), og = sigm(pre[3]);
      c_state = fg * c_state + ig * gg;
      float hv = og * tanhx(c_state);
      ushort uh = f2bf(hv);
      ushort ul = f2bf(hv - bf2f(uh));
      size_t ho = (size_t)(cur ^ 1) * Bsz * Hh + (size_t)(b0 + cb) * Hh + j0 + cj;
      unsigned uhw = uh, ulw = ul;
      asm volatile("global_store_short %0, %1, off sc0 sc1" :: "v"(hhi + ho), "v"(uhw));
      asm volatile("global_store_short %0, %1, off sc0 sc1" :: "v"(hlo + ho), "v"(ulw));
    }

    group_barrier(flags, hb, tid, (unsigned)(t + 2));
    cur ^= 1;
  }

  // ---- epilogue: wgs hb==0 compute FC for their 32 batches ----
  if (hb == 0) {
    const u64* Hf = (const u64*)(hhi + (size_t)cur * Bsz * Hh);
    const u64* Lf = (const u64*)(hlo + (size_t)cur * Bsz * Hh);
    int b = tid >> 4, lj = tid & 15;
    float p = 0.0f;
    for (int jq = lj; jq < Hh / 4; jq += 16) {
      size_t o = (size_t)(b0 + b) * (Hh / 4) + jq;
      u64 uh = __hip_atomic_load(Hf + o, __ATOMIC_RELAXED, __HIP_MEMORY_SCOPE_AGENT);
      u64 ul = __hip_atomic_load(Lf + o, __ATOMIC_RELAXED, __HIP_MEMORY_SCOPE_AGENT);
      #pragma unroll
      for (int e = 0; e < 4; ++e) {
        float hv = bf2f((ushort)(uh >> (16 * e))) + bf2f((ushort)(ul >> (16 * e)));
        p += hv * fcw[4 * jq + e];
      }
    }
    __syncthreads();
    ((float*)gates2)[tid] = p;
    __syncthreads();
    if (lj == 0) {
      float s = 0.0f;
      #pragma unroll
      for (int r = 0; r < 16; ++r) s += ((float*)gates2)[(b << 4) + r];
      out[b0 + b] = s + fcb[0];
    }
  }
}

extern "C" void kernel_launch(void* const* d_in, const int* in_sizes, int n_in,
                              void* d_out, int out_size, void* d_ws, size_t ws_size,
                              hipStream_t stream) {
  const float* x   = (const float*)d_in[0];
  const float* Wih = (const float*)d_in[1];
  const float* Whh = (const float*)d_in[2];
  const float* bih = (const float*)d_in[3];
  const float* bhh = (const float*)d_in[4];
  const float* fcw = (const float*)d_in[5];
  const float* fcb = (const float*)d_in[6];
  float* out = (float*)d_out;
  char*  ws  = (char*)d_ws;

  hipLaunchKernelGGL(init_ws, dim3(1), dim3(CTRL_UINTS), 0, stream,
                     (unsigned*)(ws + BAR_OFF));
  hipLaunchKernelGGL(lstm_kernel, dim3(NWG), dim3(NTHR), 0, stream,
                     x, Wih, Whh, bih, bhh, fcw, fcb, out, ws);
}

// Round 13
// 1928.156 us; speedup vs baseline: 1617.1260x; 1.2462x over previous
//
#include <hip/hip_runtime.h>

// SimpleLSTM B=256, T=512, I=3, H=512. out = fc(h_T).
// R13 = R12 structure (known-pass 2.40ms) with numerics switched to fp16:
//  - h exchanged as ONE fp16 plane (was bf16 hi+lo): A-loads 8->4, stores 2->1.
//  - W in LDS as f16 split: whiF = f16(W), wloF = f16((W - f16(W)) * 1024)
//    (scale keeps lo out of f16 subnormal range; folded back at combine).
//  - MFMA: mfma_f32_16x16x32_f16, 2 terms (hi, scaled-lo in separate accs),
//    32 MFMAs/wave (was 48). acc = hi + lo/1024 before LDS reduction.
//  - c_state stays fp32 in registers; accuracy set by h fp16 quantization
//    (predicted absmax ~5e-4 vs threshold 1.35e-3).
// Everything else identical: 256 wgs x 512 thr, waves (m, ks), flag-array
// LLC barrier, fragment-linear W, pad-20 gates2, batched GLOAD sc0sc1.

#define Hh   512
#define Bsz  256
#define Tt   512

#define MB   32
#define HS   16
#define NROW 64
#define NTHR 512
#define NWG  256

typedef float    f32x4 __attribute__((ext_vector_type(4)));
typedef _Float16 f16x8 __attribute__((ext_vector_type(8)));
typedef unsigned long long u64;

#define PLANE_SZ (2 * Bsz * Hh * 2)          // 512 KB: [2][256][512] f16
#define BAR_OFF  PLANE_SZ
#define CTRL_UINTS 512                       // [256 + bb*32 + hb] = arrival flags

__device__ __forceinline__ float sigm(float v)  { return 1.0f / (1.0f + __expf(-v)); }
__device__ __forceinline__ float tanhx(float v) { return 2.0f / (1.0f + __expf(-2.0f * v)) - 1.0f; }

__device__ __forceinline__ ushort f2h(float f) {      // RNE f32 -> f16 bits
  return __builtin_bit_cast(ushort, (_Float16)f);
}
__device__ __forceinline__ float h2f(ushort u) {
  return (float)__builtin_bit_cast(_Float16, u);
}

#define GLOAD(dst, base, imm)                                            \
  asm volatile("global_load_dwordx4 %0, %1, off offset:%c2 sc0 sc1"      \
               : "=v"(dst) : "v"(base), "i"(imm))

// Flag barrier at LLC (R12-validated). Arrival: tid0 stores monotone target
// to own flag after vmcnt drain + syncthreads. Exit: wave0 polls all 32
// flags (poll first, sleep on miss), __all releases, syncthreads broadcasts.
__device__ __forceinline__ void group_barrier(unsigned* flags, int hb, int tid, unsigned target) {
  asm volatile("s_waitcnt vmcnt(0)" ::: "memory");
  __syncthreads();
  if (tid == 0) {
    unsigned v = target;
    asm volatile("global_store_dword %0, %1, off sc0 sc1"
                 :: "v"(flags + hb), "v"(v) : "memory");
  }
  if (tid < 64) {
    const unsigned* fp = flags + (tid & 31);
    unsigned v;
    for (;;) {
      asm volatile("global_load_dword %0, %1, off sc0 sc1\n\t"
                   "s_waitcnt vmcnt(0)" : "=v"(v) : "v"(fp) : "memory");
      if (__all((int)(v >= target))) break;
      __builtin_amdgcn_s_sleep(1);
    }
  }
  __syncthreads();
}

__global__ void init_ws(unsigned* ctrl) {
  ctrl[threadIdx.x] = 0u;
}

__global__ __launch_bounds__(NTHR, 2)
void lstm_kernel(const float* __restrict__ x,   const float* __restrict__ Wih,
                 const float* __restrict__ Whh, const float* __restrict__ bih,
                 const float* __restrict__ bhh, const float* __restrict__ fcw,
                 const float* __restrict__ fcb, float* __restrict__ out,
                 char* __restrict__ ws)
{
  const int tid = threadIdx.x;
  const int wg  = blockIdx.x;
  const int bb  = wg & 7;
  const int hb  = wg >> 3;
  const int j0  = hb * HS;
  const int b0  = bb * MB;

  ushort*   hpl   = (ushort*)ws;             // fp16 h planes [2][256][512]
  unsigned* flags = (unsigned*)(ws + BAR_OFF) + 256 + bb * 32;

  // Fragment-linear W (f16 split): whiF[((q*16 + kblk)*64 + lane)*8 + e]
  __shared__ ushort whiF[4 * 16 * 64 * 8];   // 64 KB: f16(W)
  __shared__ ushort wloF[4 * 16 * 64 * 8];   // 64 KB: f16((W - hi) * 1024)
  __shared__ float  gates2[2][4][MB][20];    // two-stage K-partials, pad 20
  __shared__ float  wih_s[NROW][3];
  __shared__ float  bsum[NROW];
  __shared__ float  xs[MB][3];

  if (tid < NROW) {
    int qq = tid >> 4, jj = tid & 15;
    int grow = qq * Hh + j0 + jj;
    wih_s[tid][0] = Wih[grow * 3 + 0];
    wih_s[tid][1] = Wih[grow * 3 + 1];
    wih_s[tid][2] = Wih[grow * 3 + 2];
    bsum[tid] = bih[grow] + bhh[grow];
  }

  for (int idx = tid; idx < NROW * 64; idx += NTHR) {
    int row = idx >> 6, seg = idx & 63;
    int qq = row >> 4, jj = row & 15;
    const float* src = Whh + (size_t)(qq * Hh + j0 + jj) * Hh + seg * 8;
    float4 w0 = *(const float4*)(src);
    float4 w1 = *(const float4*)(src + 4);
    float wv[8] = {w0.x, w0.y, w0.z, w0.w, w1.x, w1.y, w1.z, w1.w};
    unsigned uhi[4], ulo[4];
    #pragma unroll
    for (int p = 0; p < 4; ++p) {
      ushort h0 = f2h(wv[2*p]);
      ushort h1 = f2h(wv[2*p+1]);
      ushort l0 = f2h((wv[2*p]   - h2f(h0)) * 1024.0f);
      ushort l1 = f2h((wv[2*p+1] - h2f(h1)) * 1024.0f);
      uhi[p] = (unsigned)h0 | ((unsigned)h1 << 16);
      ulo[p] = (unsigned)l0 | ((unsigned)l1 << 16);
    }
    int kblk = seg >> 2, lkk = seg & 3;
    int dst = ((qq * 16 + kblk) * 64 + lkk * 16 + jj) * 8;
    *(uint4*)&whiF[dst] = make_uint4(uhi[0], uhi[1], uhi[2], uhi[3]);
    *(uint4*)&wloF[dst] = make_uint4(ulo[0], ulo[1], ulo[2], ulo[3]);
  }

  // ---- zero h_0 slice (buffer 0) ----
  {
    int b = tid >> 4, jj = tid & 15;
    size_t o = (size_t)(b0 + b) * Hh + j0 + jj;
    __hip_atomic_store(&hpl[o], (ushort)0, __ATOMIC_RELAXED, __HIP_MEMORY_SCOPE_AGENT);
  }
  group_barrier(flags, hb, tid, 1u);

  const int l   = tid & 63;
  const int wid = tid >> 6;
  const int m   = wid >> 2;            // batch half (0..1)
  const int ks  = wid & 3;             // K quarter (0..3)
  const int lm  = l & 15;
  const int lk  = l >> 4;              // 0..3

  const size_t aoff  = (size_t)(b0 + m * 16 + lm) * Hh + ks * 128 + lk * 8;
  const int    wq0   = ks * 2048 + l * 8;   // + q*8192 + u*512 (ushort idx)

  const int cb = tid >> 4;
  const int cj = tid & 15;
  float c_state = 0.0f;

  int cur = 0;
  for (int t = 0; t < Tt; ++t) {
    if (tid < MB * 3) {
      int b = tid / 3, ii = tid - b * 3;
      xs[b][ii] = x[(size_t)(b0 + b) * (Tt * 3) + t * 3 + ii];
    }

    // ---- 4 pipelined A loads (distinct K-quarter, fp16) ----
    const char* pH = (const char*)(hpl + (size_t)cur * Bsz * Hh + aoff);
    f32x4 AH[4];
    GLOAD(AH[0], pH, 0);  GLOAD(AH[1], pH, 64);  GLOAD(AH[2], pH, 128); GLOAD(AH[3], pH, 192);
    asm volatile("s_waitcnt vmcnt(0)" ::: "memory");
    __builtin_amdgcn_sched_barrier(0);

    // ---- 4 quadrants x 4 k-blocks x 2 terms (hi, scaled lo) = 32 MFMAs ----
    f32x4 h0 = {0,0,0,0}, h1 = {0,0,0,0}, h2 = {0,0,0,0}, h3 = {0,0,0,0};
    f32x4 l0 = {0,0,0,0}, l1 = {0,0,0,0}, l2 = {0,0,0,0}, l3 = {0,0,0,0};
    #pragma unroll
    for (int u = 0; u < 4; ++u) {
      f16x8 ah = __builtin_bit_cast(f16x8, AH[u]);
      const int fo = wq0 + u * 512;
      {
        f16x8 bh = *(const f16x8*)&whiF[0 * 8192 + fo];
        f16x8 bl = *(const f16x8*)&wloF[0 * 8192 + fo];
        h0 = __builtin_amdgcn_mfma_f32_16x16x32_f16(ah, bh, h0, 0, 0, 0);
        l0 = __builtin_amdgcn_mfma_f32_16x16x32_f16(ah, bl, l0, 0, 0, 0);
      }
      {
        f16x8 bh = *(const f16x8*)&whiF[1 * 8192 + fo];
        f16x8 bl = *(const f16x8*)&wloF[1 * 8192 + fo];
        h1 = __builtin_amdgcn_mfma_f32_16x16x32_f16(ah, bh, h1, 0, 0, 0);
        l1 = __builtin_amdgcn_mfma_f32_16x16x32_f16(ah, bl, l1, 0, 0, 0);
      }
      {
        f16x8 bh = *(const f16x8*)&whiF[2 * 8192 + fo];
        f16x8 bl = *(const f16x8*)&wloF[2 * 8192 + fo];
        h2 = __builtin_amdgcn_mfma_f32_16x16x32_f16(ah, bh, h2, 0, 0, 0);
        l2 = __builtin_amdgcn_mfma_f32_16x16x32_f16(ah, bl, l2, 0, 0, 0);
      }
      {
        f16x8 bh = *(const f16x8*)&whiF[3 * 8192 + fo];
        f16x8 bl = *(const f16x8*)&wloF[3 * 8192 + fo];
        h3 = __builtin_amdgcn_mfma_f32_16x16x32_f16(ah, bh, h3, 0, 0, 0);
        l3 = __builtin_amdgcn_mfma_f32_16x16x32_f16(ah, bl, l3, 0, 0, 0);
      }
    }
    const float ls = 1.0f / 1024.0f;
    f32x4 acc0 = h0 + l0 * ls;
    f32x4 acc1 = h1 + l1 * ls;
    f32x4 acc2 = h2 + l2 * ls;
    f32x4 acc3 = h3 + l3 * ls;

    // ---- two-stage K-partial reduction in LDS ----
    const int rrow = m * 16 + lk * 4;
    if (ks < 2) {
      #pragma unroll
      for (int r = 0; r < 4; ++r) {
        gates2[ks][0][rrow + r][lm] = acc0[r];
        gates2[ks][1][rrow + r][lm] = acc1[r];
        gates2[ks][2][rrow + r][lm] = acc2[r];
        gates2[ks][3][rrow + r][lm] = acc3[r];
      }
    }
    __syncthreads();
    if (ks >= 2) {
      #pragma unroll
      for (int r = 0; r < 4; ++r) {
        gates2[ks - 2][0][rrow + r][lm] += acc0[r];
        gates2[ks - 2][1][rrow + r][lm] += acc1[r];
        gates2[ks - 2][2][rrow + r][lm] += acc2[r];
        gates2[ks - 2][3][rrow + r][lm] += acc3[r];
      }
    }
    __syncthreads();

    // ---- gate combine + direct coalesced fp16 h store ----
    {
      float xv0 = xs[cb][0], xv1 = xs[cb][1], xv2 = xs[cb][2];
      float pre[4];
      #pragma unroll
      for (int qq = 0; qq < 4; ++qq) {
        int r = qq * 16 + cj;
        pre[qq] = gates2[0][qq][cb][cj] + gates2[1][qq][cb][cj] + bsum[r]
                + xv0 * wih_s[r][0] + xv1 * wih_s[r][1] + xv2 * wih_s[r][2];
      }
      float ig = sigm(pre[0]), fg = sigm(pre[1]);
      float gg = tanhx(pre[2]), og = sigm(pre[3]);
      c_state = fg * c_state + ig * gg;
      float hv = og * tanhx(c_state);
      unsigned uhw = f2h(hv);
      size_t ho = (size_t)(cur ^ 1) * Bsz * Hh + (size_t)(b0 + cb) * Hh + j0 + cj;
      asm volatile("global_store_short %0, %1, off sc0 sc1" :: "v"(hpl + ho), "v"(uhw));
    }

    group_barrier(flags, hb, tid, (unsigned)(t + 2));
    cur ^= 1;
  }

  // ---- epilogue: wgs hb==0 compute FC for their 32 batches ----
  if (hb == 0) {
    const u64* Hf = (const u64*)(hpl + (size_t)cur * Bsz * Hh);
    int b = tid >> 4, lj = tid & 15;
    float p = 0.0f;
    for (int jq = lj; jq < Hh / 4; jq += 16) {
      size_t o = (size_t)(b0 + b) * (Hh / 4) + jq;
      u64 uh = __hip_atomic_load(Hf + o, __ATOMIC_RELAXED, __HIP_MEMORY_SCOPE_AGENT);
      #pragma unroll
      for (int e = 0; e < 4; ++e)
        p += h2f((ushort)(uh >> (16 * e))) * fcw[4 * jq + e];
    }
    __syncthreads();
    ((float*)gates2)[tid] = p;
    __syncthreads();
    if (lj == 0) {
      float s = 0.0f;
      #pragma unroll
      for (int r = 0; r < 16; ++r) s += ((float*)gates2)[(b << 4) + r];
      out[b0 + b] = s + fcb[0];
    }
  }
}

extern "C" void kernel_launch(void* const* d_in, const int* in_sizes, int n_in,
                              void* d_out, int out_size, void* d_ws, size_t ws_size,
                              hipStream_t stream) {
  const float* x   = (const float*)d_in[0];
  const float* Wih = (const float*)d_in[1];
  const float* Whh = (const float*)d_in[2];
  const float* bih = (const float*)d_in[3];
  const float* bhh = (const float*)d_in[4];
  const float* fcw = (const float*)d_in[5];
  const float* fcb = (const float*)d_in[6];
  float* out = (float*)d_out;
  char*  ws  = (char*)d_ws;

  hipLaunchKernelGGL(init_ws, dim3(1), dim3(CTRL_UINTS), 0, stream,
                     (unsigned*)(ws + BAR_OFF));
  hipLaunchKernelGGL(lstm_kernel, dim3(NWG), dim3(NTHR), 0, stream,
                     x, Wih, Whh, bih, bhh, fcw, fcb, out, ws);
}